// Round 1
// baseline (190.072 us; speedup 1.0000x reference)
//
#include <hip/hip_runtime.h>
#include <hip/hip_bf16.h>
#include <stdint.h>

// Problem constants (B, L, D, T) = (2, 2048, 1536, 2)
#define B_ 2
#define L_ 2048
#define D_ 1536

typedef __attribute__((ext_vector_type(4))) float  f32x4;
typedef __attribute__((ext_vector_type(8))) __bf16 bf16x8;

__device__ __forceinline__ unsigned short f2bf(float f) {
  unsigned int u = __float_as_uint(f);
  u += 0x7fffu + ((u >> 16) & 1u);   // RNE
  return (unsigned short)(u >> 16);
}

// Stage 1: hs(fp32) -> X(bf16), and P[t] = hs * Wp[t] (bf16), t in {0,1}
__global__ __launch_bounds__(256) void conv_kernel(
    const float* __restrict__ hs, const float* __restrict__ W,
    unsigned short* __restrict__ X, unsigned short* __restrict__ P) {
  const int idx  = blockIdx.x * 256 + threadIdx.x;
  const int base = idx * 4;                       // 4 consecutive d per thread
  const int d    = base % D_;                     // row-major (b,i,d); D_%4==0
  const float4 h  = *(const float4*)(hs + base);
  const float4 w0 = *(const float4*)(W + d);            // Wp[0, d..d+3]
  const float4 w1 = *(const float4*)(W + 2 * D_ + d);   // Wp[1, d..d+3]
  ushort4 x, p0, p1;
  x.x  = f2bf(h.x);        x.y  = f2bf(h.y);        x.z  = f2bf(h.z);        x.w  = f2bf(h.w);
  p0.x = f2bf(h.x * w0.x); p0.y = f2bf(h.y * w0.y); p0.z = f2bf(h.z * w0.z); p0.w = f2bf(h.w * w0.w);
  p1.x = f2bf(h.x * w1.x); p1.y = f2bf(h.y * w1.y); p1.z = f2bf(h.z * w1.z); p1.w = f2bf(h.w * w1.w);
  *(ushort4*)(X + base) = x;
  *(ushort4*)(P + base) = p0;
  *(ushort4*)(P + (size_t)B_ * L_ * D_ + base) = p1;
}

__device__ __forceinline__ void async16(const void* g, const void* l) {
  __builtin_amdgcn_global_load_lds(
      (const __attribute__((address_space(1))) void*)g,
      (__attribute__((address_space(3))) void*)l, 16, 0, 0);
}

// Stage 2: out[b,i,j,(t0,t1)] = P_t[b,i,:] . X[b,j,:] + bias[t]
// Tile 128x128, BK=32, 256 threads (4 waves, 2x2 of 64x64), both t per block.
__global__ __launch_bounds__(256) void gemm_kernel(
    const unsigned short* __restrict__ X, const unsigned short* __restrict__ P,
    const float* __restrict__ bias, float2* __restrict__ out) {
  __shared__ unsigned short As0[128 * 32];
  __shared__ unsigned short As1[128 * 32];
  __shared__ unsigned short Bs [128 * 32];

  const int tid = threadIdx.x;
  const int I0  = blockIdx.y * 128;   // i tile
  const int J0  = blockIdx.x * 128;   // j tile
  const int bz  = blockIdx.z;

  // ---- staging geometry: thread tid fills LDS slot (row=tid>>2, chunkslot=tid&3),
  // 16B per load. XOR swizzle: slot cs holds global chunk gc = cs ^ ((row>>1)&3)
  // so ds_read_b128 spreads over 8 bank-groups (2-way == free).
  const int srow = tid >> 2;
  const int cs   = tid & 3;
  const int gc   = cs ^ ((srow >> 1) & 3);
  const int scol = gc * 8;                       // global d-chunk (elements)
  const int ldst = tid * 8;                      // LDS dest (elements) == row*32 + cs*8

  const size_t planeB = (size_t)B_ * L_ * D_;
  const unsigned short* pA0 = P + (size_t)bz * L_ * D_ + (size_t)(I0 + srow) * D_ + scol;
  const unsigned short* pA1 = pA0 + planeB;      // t=1 plane
  const unsigned short* pB  = X + (size_t)bz * L_ * D_ + (size_t)(J0 + srow) * D_ + scol;

  // ---- compute geometry
  const int lane = tid & 63;
  const int w    = tid >> 6;
  const int wi   = (w & 1) * 64;
  const int wj   = (w >> 1) * 64;
  const int lr   = lane & 15;
  const int q    = lane >> 4;
  const int rsw  = (lr >> 1) & 3;                // swizzle term for reads
  const int ccol = (q ^ rsw) * 8;                // LDS chunk for quad q

  int aoff[4], boff[4];
#pragma unroll
  for (int m = 0; m < 4; ++m) {
    aoff[m] = (wi + m * 16 + lr) * 32 + ccol;
    boff[m] = (wj + m * 16 + lr) * 32 + ccol;
  }

  f32x4 acc0[4][4] = {};
  f32x4 acc1[4][4] = {};

  for (int k = 0; k < D_ / 32; ++k) {
    async16(pA0,            As0 + ldst);
    async16(pA0 + 64 * D_,  As0 + ldst + 2048);
    async16(pA1,            As1 + ldst);
    async16(pA1 + 64 * D_,  As1 + ldst + 2048);
    async16(pB,             Bs  + ldst);
    async16(pB  + 64 * D_,  Bs  + ldst + 2048);
    pA0 += 32; pA1 += 32; pB += 32;
    __syncthreads();   // vmcnt(0) drain: LDS tiles valid

    bf16x8 a0f[4], a1f[4], bff[4];
#pragma unroll
    for (int m = 0; m < 4; ++m) {
      a0f[m] = *(const bf16x8*)(As0 + aoff[m]);
      a1f[m] = *(const bf16x8*)(As1 + aoff[m]);
    }
#pragma unroll
    for (int n = 0; n < 4; ++n) bff[n] = *(const bf16x8*)(Bs + boff[n]);
#pragma unroll
    for (int m = 0; m < 4; ++m)
#pragma unroll
      for (int n = 0; n < 4; ++n) {
        acc0[m][n] = __builtin_amdgcn_mfma_f32_16x16x32_bf16(a0f[m], bff[n], acc0[m][n], 0, 0, 0);
        acc1[m][n] = __builtin_amdgcn_mfma_f32_16x16x32_bf16(a1f[m], bff[n], acc1[m][n], 0, 0, 0);
      }
    __syncthreads();   // all reads done before next overwrite
  }

  // ---- epilogue: C/D layout col(j)=lane&15, row(i)=quad*4+reg
  const float bias0 = bias[0], bias1 = bias[1];
#pragma unroll
  for (int m = 0; m < 4; ++m) {
#pragma unroll
    for (int r = 0; r < 4; ++r) {
      const int i = I0 + wi + m * 16 + q * 4 + r;
      float2* orow = out + (size_t)(bz * L_ + i) * L_ + (J0 + wj + lr);
#pragma unroll
      for (int n = 0; n < 4; ++n) {
        float2 v;
        v.x = acc0[m][n][r] + bias0;
        v.y = acc1[m][n][r] + bias1;
        orow[n * 16] = v;
      }
    }
  }
}

extern "C" void kernel_launch(void* const* d_in, const int* in_sizes, int n_in,
                              void* d_out, int out_size, void* d_ws, size_t ws_size,
                              hipStream_t stream) {
  const float* hs   = (const float*)d_in[0];
  const float* W    = (const float*)d_in[1];
  const float* bias = (const float*)d_in[2];

  unsigned short* X = (unsigned short*)d_ws;                 // B*L*D bf16
  unsigned short* P = X + (size_t)B_ * L_ * D_;              // T*B*L*D bf16

  const int nconv = (B_ * L_ * D_ / 4) / 256;                // 6144 blocks
  conv_kernel<<<nconv, 256, 0, stream>>>(hs, W, X, P);

  dim3 grid(L_ / 128, L_ / 128, B_);                         // 16 x 16 x 2
  gemm_kernel<<<grid, 256, 0, stream>>>(X, P, bias, (float2*)d_out);
}

// Round 2
// 156.583 us; speedup vs baseline: 1.2139x; 1.2139x over previous
//
#include <hip/hip_runtime.h>
#include <hip/hip_bf16.h>
#include <stdint.h>

// Problem constants (B, L, D, T) = (2, 2048, 1536, 2)
#define B_ 2
#define L_ 2048
#define D_ 1536

typedef __attribute__((ext_vector_type(4))) float  f32x4;
typedef __attribute__((ext_vector_type(8))) __bf16 bf16x8;

__device__ __forceinline__ unsigned short f2bf(float f) {
  unsigned int u = __float_as_uint(f);
  u += 0x7fffu + ((u >> 16) & 1u);   // RNE
  return (unsigned short)(u >> 16);
}

// Stage 1: hs(fp32) -> X(bf16), and P[t] = hs * Wp[t] (bf16), t in {0,1}
__global__ __launch_bounds__(256) void conv_kernel(
    const float* __restrict__ hs, const float* __restrict__ W,
    unsigned short* __restrict__ X, unsigned short* __restrict__ P) {
  const int idx  = blockIdx.x * 256 + threadIdx.x;
  const int base = idx * 4;                       // 4 consecutive d per thread
  const int d    = base % D_;                     // row-major (b,i,d); D_%4==0
  const float4 h  = *(const float4*)(hs + base);
  const float4 w0 = *(const float4*)(W + d);            // Wp[0, d..d+3]
  const float4 w1 = *(const float4*)(W + 2 * D_ + d);   // Wp[1, d..d+3]
  ushort4 x, p0, p1;
  x.x  = f2bf(h.x);        x.y  = f2bf(h.y);        x.z  = f2bf(h.z);        x.w  = f2bf(h.w);
  p0.x = f2bf(h.x * w0.x); p0.y = f2bf(h.y * w0.y); p0.z = f2bf(h.z * w0.z); p0.w = f2bf(h.w * w0.w);
  p1.x = f2bf(h.x * w1.x); p1.y = f2bf(h.y * w1.y); p1.z = f2bf(h.z * w1.z); p1.w = f2bf(h.w * w1.w);
  *(ushort4*)(X + base) = x;
  *(ushort4*)(P + base) = p0;
  *(ushort4*)(P + (size_t)B_ * L_ * D_ + base) = p1;
}

__device__ __forceinline__ void async16(const void* g, const void* l) {
  __builtin_amdgcn_global_load_lds(
      (const __attribute__((address_space(1))) void*)g,
      (__attribute__((address_space(3))) void*)l, 16, 0, 0);
}

// Stage 2 (de-fused t): out[b,i,j,t] = P_t[b,i,:] . X[b,j,:] + bias[t]
// Grid: 1024 blocks (1D), 256 threads. 128x128 tile, BK=32, double-buffered
// LDS with a single barrier per K-iter (prefetch drain overlaps compute).
// Block-id decode is XCD-aware: id%8 = XCD; t-pairs of the same (b,i,j) tile
// are 8 ids apart (same XCD, near-concurrent) so their interleaved fp32
// stores merge in that XCD's L2.
__global__ __launch_bounds__(256, 4) void gemm_kernel(
    const unsigned short* __restrict__ X, const unsigned short* __restrict__ P,
    const float* __restrict__ bias, float* __restrict__ out) {
  __shared__ unsigned short As[2 * 128 * 32];
  __shared__ unsigned short Bs[2 * 128 * 32];

  const int tid = threadIdx.x;

  // ---- block-id decode: id = xcd + 8*(t + 2*(within + 16*pp))
  const int id     = blockIdx.x;
  const int xcd    = id & 7;
  const int u      = id >> 3;
  const int t      = u & 1;
  const int v      = u >> 1;          // 0..63
  const int within = v & 15;          // position in 4x4 tile patch
  const int pp     = v >> 4;          // 0..3 (patch group, outer in time)
  const int Pp     = pp * 8 + xcd;    // patch 0..31 (16 per b)
  const int bz     = Pp >> 4;
  const int pr     = Pp & 15;
  const int I0     = ((pr >> 2) * 4 + (within >> 2)) * 128;
  const int J0     = ((pr & 3)  * 4 + (within & 3))  * 128;

  // ---- staging geometry: thread tid fills LDS slot (row=tid>>2, slot=tid&3),
  // 16B per load. XOR swizzle: slot cs holds global chunk gc = cs ^ ((row>>1)&3).
  const int srow = tid >> 2;
  const int cs   = tid & 3;
  const int gc   = cs ^ ((srow >> 1) & 3);
  const int scol = gc * 8;                       // element offset of d-chunk
  const int ldst = tid * 8;                      // LDS dest slot (elements)

  const unsigned short* pA =
      P + (size_t)t * B_ * L_ * D_ + ((size_t)(bz * L_ + I0 + srow)) * D_ + scol;
  const unsigned short* pB =
      X + ((size_t)(bz * L_ + J0 + srow)) * D_ + scol;

  // ---- compute geometry (2x2 waves of 64x64)
  const int lane = tid & 63;
  const int w    = tid >> 6;
  const int wi   = (w & 1) * 64;
  const int wj   = (w >> 1) * 64;
  const int lr   = lane & 15;
  const int q    = lane >> 4;
  const int ccol = (q ^ ((lr >> 1) & 3)) * 8;    // read-side swizzle

  int aoff[4], boff[4];
#pragma unroll
  for (int m = 0; m < 4; ++m) {
    aoff[m] = (wi + m * 16 + lr) * 32 + ccol;
    boff[m] = (wj + m * 16 + lr) * 32 + ccol;
  }

  f32x4 acc[4][4] = {};

#define STAGE(buf, koff)                                          \
  do {                                                            \
    async16(pA + (koff),           As + (buf) * 4096 + ldst);     \
    async16(pA + (koff) + 64 * D_, As + (buf) * 4096 + ldst + 2048); \
    async16(pB + (koff),           Bs + (buf) * 4096 + ldst);     \
    async16(pB + (koff) + 64 * D_, Bs + (buf) * 4096 + ldst + 2048); \
  } while (0)

  STAGE(0, 0);
  for (int k = 0; k < D_ / 32; ++k) {
    __syncthreads();                 // drains prefetch (vmcnt0) + prior reads (lgkm0)
    if (k < D_ / 32 - 1) STAGE((k + 1) & 1, (k + 1) * 32);
    const unsigned short* Ab = As + (k & 1) * 4096;
    const unsigned short* Bb = Bs + (k & 1) * 4096;
    bf16x8 af[4], bf_[4];
#pragma unroll
    for (int m = 0; m < 4; ++m) af[m]  = *(const bf16x8*)(Ab + aoff[m]);
#pragma unroll
    for (int n = 0; n < 4; ++n) bf_[n] = *(const bf16x8*)(Bb + boff[n]);
#pragma unroll
    for (int m = 0; m < 4; ++m)
#pragma unroll
      for (int n = 0; n < 4; ++n)
        acc[m][n] = __builtin_amdgcn_mfma_f32_16x16x32_bf16(af[m], bf_[n], acc[m][n], 0, 0, 0);
  }
#undef STAGE

  // ---- epilogue: C/D layout col(j)=lane&15, row(i)=quad*4+reg
  const float bt = bias[t];
#pragma unroll
  for (int m = 0; m < 4; ++m) {
#pragma unroll
    for (int r = 0; r < 4; ++r) {
      const int i = I0 + wi + m * 16 + q * 4 + r;
      float* orow = out + (((size_t)(bz * L_ + i)) * L_ + (J0 + wj + lr)) * 2 + t;
#pragma unroll
      for (int n = 0; n < 4; ++n) orow[n * 32] = acc[m][n][r] + bt;
    }
  }
}

extern "C" void kernel_launch(void* const* d_in, const int* in_sizes, int n_in,
                              void* d_out, int out_size, void* d_ws, size_t ws_size,
                              hipStream_t stream) {
  const float* hs   = (const float*)d_in[0];
  const float* W    = (const float*)d_in[1];
  const float* bias = (const float*)d_in[2];

  unsigned short* X = (unsigned short*)d_ws;                 // B*L*D bf16
  unsigned short* P = X + (size_t)B_ * L_ * D_;              // T*B*L*D bf16

  const int nconv = (B_ * L_ * D_ / 4) / 256;                // 6144 blocks
  conv_kernel<<<nconv, 256, 0, stream>>>(hs, W, X, P);

  gemm_kernel<<<1024, 256, 0, stream>>>(X, P, bias, (float*)d_out);
}